// Round 17
// baseline (534.875 us; speedup 1.0000x reference)
//
#include <hip/hip_runtime.h>

// convEP: 10-step EP relaxation, MFMA fp16 2-way-split convs (fp32-equivalent).
//   s0' = rho(fc(s1));  s1' = rho(pool(conv0(s2)) + fc^T(s0));  s2' = rho(p2 + convT(unpool(s1, idx1)))
// fp32 x = xh + 2^-12*xl' (fp16 planes, lo pre-scaled 2^12 to stay fp16-normal).
// MFMA 16x16x32_f16: A[m=l16][k=quad*8+j], B[k=quad*8+j][n=l16], C/D: col=l16, row=quad*4+reg.
// R30: revert R29's cooperative kernel (launch silently rejected -> all-zero output;
// LEDGER: never ship unchecked coop launch in this harness). Keep R28 structure; harvest
// R29's sound folds with ORDINARY kernels:
//  (a) cTcomb DELETED: s2_7/s2_10 canonical dual-store in convTF epilogue (t=6/9);
//      s0_7 by conv0F designated blocks at t=7 (s0l IS s0_7); s0_10 by convTF designated
//      blocks at t=9 (reads s0part buf0 from the earlier conv0F dispatch).
//  (b) k_prep = wprep+p2 merged (1056 blocks, branch on blockIdx) + s2pk zeroing folded
//      (memset dispatch dropped). Dispatches 24 -> 21.

typedef _Float16 half8 __attribute__((ext_vector_type(8)));
typedef _Float16 half4 __attribute__((ext_vector_type(4)));
typedef _Float16 half2v __attribute__((ext_vector_type(2)));
typedef float f32x4 __attribute__((ext_vector_type(4)));
#define MFMA_F16(A, B, C) __builtin_amdgcn_mfma_f32_16x16x32_f16((A), (B), (C), 0, 0, 0)
#define LO_SCALE 2.44140625e-4f   // 2^-12

static __device__ __forceinline__ float rho_(float x) {
  return fminf(fmaxf(x, 0.0f), 1.0f);
}
static __device__ __forceinline__ void split2(float v, _Float16& h, _Float16& l) {
  if (fabsf(v) < 6.1035156e-5f) {
    h = (_Float16)0.f;
    l = (_Float16)(v * 4096.f);
  } else {
    h = (_Float16)v;
    l = (_Float16)((v - (float)h) * 4096.f);
  }
}

// ---------------- K0: merged prep: weight split + fcwp + s0part + s2pk zero + p2t ----------------
// blocks 0..799: wprep body (+ s2pk stride-zero); blocks 800..1055: p2 body.
__global__ __launch_bounds__(256) void k_prep(
    const float* __restrict__ w0, const float* __restrict__ fcb,
    const float* __restrict__ fcw,
    const float* __restrict__ data, const float* __restrict__ conv1w,
    const float* __restrict__ conv1b,
    _Float16* __restrict__ wA0h, _Float16* __restrict__ wA0l,
    _Float16* __restrict__ wA1h, _Float16* __restrict__ wA1l,
    float* __restrict__ fcwp, float* __restrict__ s0part,
    float* __restrict__ p2t, unsigned* __restrict__ s2pk) {
  __shared__ float ld[3][36][36];
  __shared__ float lw[16][80];
  __shared__ float lb[16];
  int blk = blockIdx.x, tid = threadIdx.x;
  if (blk < 800) {
    int i = blk * 256 + tid;   // 0..204799
    for (int j = i; j < 1048576; j += 204800) s2pk[j] = 0u;   // t=0: s2 = 0 (split(0)=0)
    if (i < 10240) {
      int k = i - (i / 10) * 10;
      s0part[i] = (i < 640) ? -fcb[k] : 0.f;
    }
    if (i < 98304) {   // fcwp: 8192 jj x 12
      int jj = i / 12, k = i - jj * 12;
      int cgpyq = jj >> 10, idx = jj & 1023;
      int cgp = cgpyq >> 2, yq = cgpyq & 3;
      int co = idx & 31, win = (idx >> 5) & 15, cgl2 = idx >> 9;
      int co_g = cgp * 64 + cgl2 * 32 + co;
      int phl = win >> 3, pw = win & 7;
      int ph = yq * 2 + phl;
      int j = co_g * 64 + ph * 8 + pw;
      fcwp[i] = (k < 10) ? fcw[k * 8192 + j] : 0.f;
    }
    {
      int cik = i & 31, t1 = i >> 5;
      int co = t1 & 127, t2 = t1 >> 7;
      int ck = t2 & 1, tap = t2 >> 1;
      float v = w0[(co * 64 + ck * 32 + cik) * 25 + tap];
      _Float16 h, l; split2(v, h, l);
      wA0h[i] = h; wA0l[i] = l;
    }
    {
      int cpk = i & 31, t1 = i >> 5;
      int o = t1 & 63, t2 = t1 >> 6;
      int c = t2 & 3, tap = t2 >> 2;
      float v = w0[((c * 32 + cpk) * 64 + o) * 25 + tap];
      _Float16 h, l; split2(v, h, l);
      wA1h[i] = h; wA1l[i] = l;
    }
    return;
  }
  // ---- p2 branch: p2t[b][pos 256][co 64] = transpose(maxpool(conv1(data))) ----
  int pb = blk - 800;
  int b = pb >> 2, cg = pb & 3;
  for (int i = tid; i < 3 * 36 * 36; i += 256) {
    int ci = i / 1296, rem = i % 1296, y = rem / 36, x = rem % 36;
    int gy = y - 2, gx = x - 2;
    float v = 0.f;
    if (gy >= 0 && gy < 32 && gx >= 0 && gx < 32)
      v = data[(b * 3 + ci) * 1024 + gy * 32 + gx];
    ld[ci][y][x] = v;
  }
  for (int i = tid; i < 16 * 75; i += 256) {
    int co = i / 75, k = i % 75;
    lw[co][k] = conv1w[(cg * 16 + co) * 75 + k];
  }
  if (tid < 16) lb[tid] = conv1b[cg * 16 + tid];
  __syncthreads();
  int ph = tid >> 4, pw = tid & 15;
  int ry = 2 * ph, rx = 2 * pw;
  for (int co = 0; co < 16; co++) {
    float bv = lb[co];
    float a00 = bv, a01 = bv, a10 = bv, a11 = bv;
    for (int ci = 0; ci < 3; ci++) {
#pragma unroll
      for (int ky = 0; ky < 5; ky++) {
#pragma unroll
        for (int kx = 0; kx < 5; kx++) {
          float wv = lw[co][(ci * 5 + ky) * 5 + kx];
          a00 += wv * ld[ci][ry + ky][rx + kx];
          a01 += wv * ld[ci][ry + ky][rx + kx + 1];
          a10 += wv * ld[ci][ry + ky + 1][rx + kx];
          a11 += wv * ld[ci][ry + ky + 1][rx + kx + 1];
        }
      }
    }
    float m = fmaxf(fmaxf(a00, a01), fmaxf(a10, a11));
    p2t[b * 16384 + tid * 64 + cg * 16 + co] = m;
  }
}

// ---------------- K2: conv0 (cg-pair x y-quarter) + pool/argmax + s1 + u + s0 FC partial ----------------
// grid (64 b, 2 cgp, 4 yq) = 512 blocks, 512 thr = 8 waves = kc(2) x cgl(2) x tg(2 taps {13,12}).
// Staging: s2pk [b][pos][ci 64]: uint4 + half4 LDS writes, 4 iters; x-zero-row pos 128.
// Combine: 4 slices [cgl][tg][32][67]; kc1 write, kc0 +=. Epilogue co-inner lanes:
// C stride-67 reads, fcwp 3xfloat4, s1p [b][jj] coalesced both sides, u 128B segments.
// s1out non-null (t=6/9): canonical dual-store. s0snap non-null (t=7): designated blocks
// (cgp==0,yq==0) write s0_7 = s0l. launch_bounds(512,4).
__global__ __launch_bounds__(512, 4) void k_conv0F(
    const unsigned* __restrict__ s2pk,
    const _Float16* __restrict__ wA0h, const _Float16* __restrict__ wA0l,
    const float* __restrict__ b0,
    const float* __restrict__ s1old,
    const float* __restrict__ s0prevPart, float* __restrict__ s0curPart,
    const float* __restrict__ fcb,
    const float* __restrict__ fcwp, float* __restrict__ s1new,
    float* __restrict__ s1out, float* __restrict__ s0snap,
    unsigned* __restrict__ u) {
  __shared__ __align__(16) _Float16 sm[18576];   // stage 37152 B; combine 4x[32][67] f32 34304 B
  __shared__ float s0l[10];
  __shared__ float s0red[8][10];
  int b = blockIdx.x, cgp = blockIdx.y, yq = blockIdx.z, tid = threadIdx.x;

  if (tid < 10) {   // s0_t = rho(sum of prev step's 8 slot partials + fcb); used in epilogue
    float s = 0.f;
#pragma unroll
    for (int sl = 0; sl < 8; sl++) s += s0prevPart[(sl * 64 + b) * 10 + tid];
    float v = rho_(s + fcb[tid]);
    s0l[tid] = v;
    if (s0snap && cgp == 0 && yq == 0) s0snap[b * 10 + tid] = v;   // t=7: s0_7 snapshot
  }

  // stage 8-row slab: s2pk[b][pos_g][ci]; 2048 uint4-tasks (128 pos x 16 ci4), 4 iters.
#pragma unroll
  for (int it = 0; it < 4; it++) {
    int idx = it * 512 + tid;
    int ci4 = (idx & 15) * 4;
    int pos = idx >> 4;                // 0..127 (ly*16+lx)
    int gy = yq * 4 - 2 + (pos >> 4);
    int lx = pos & 15;
    uint4 pk = {0u, 0u, 0u, 0u};
    if ((unsigned)gy < 16u) pk = *(const uint4*)&s2pk[b * 16384 + (gy * 16 + lx) * 64 + ci4];
    half2v h0 = __builtin_bit_cast(half2v, pk.x);
    half2v h1 = __builtin_bit_cast(half2v, pk.y);
    half2v h2 = __builtin_bit_cast(half2v, pk.z);
    half2v h3 = __builtin_bit_cast(half2v, pk.w);
    half4 hi, lo;
    hi[0] = h0[0]; hi[1] = h1[0]; hi[2] = h2[0]; hi[3] = h3[0];
    lo[0] = h0[1]; lo[1] = h1[1]; lo[2] = h2[1]; lo[3] = h3[1];
    *(half4*)(sm + pos * 72 + ci4) = hi;
    *(half4*)(sm + 9288 + pos * 72 + ci4) = lo;
  }
  // zero row (pos 128) in both planes: oob B-reads land here
  if (tid < 72) {
    sm[9216 + tid] = (_Float16)0.f;          // hi plane, pos 128
    sm[9288 + 9216 + tid] = (_Float16)0.f;   // lo plane, pos 128
  }
  __syncthreads();

  int lane = tid & 63, w = tid >> 6;
  int kc = w & 1, cgl = (w >> 1) & 1, tg = w >> 2;
  int l16 = lane & 15, quad = lane >> 4;

  f32x4 acch[4][2], accl[4][2];   // [nt: 4 rows][mt]  (bias in epilogue)
#pragma unroll
  for (int nt = 0; nt < 4; nt++)
#pragma unroll
    for (int mt = 0; mt < 2; mt++) {
      f32x4 z; z[0] = 0.f; z[1] = 0.f; z[2] = 0.f; z[3] = 0.f;
      acch[nt][mt] = z; accl[nt][mt] = z;
    }

  const int bofs = kc * 32 + quad * 8;
  const int Abase = (kc * 128 + (cgp * 2 + cgl) * 32 + l16) * 32 + quad * 8;  // + tap*8192 + mt*512
  const int tapLo = tg ? 13 : 0;
  const int tapEnd = tg ? 25 : 13;

  half8 ahc[2], alc[2];
#pragma unroll
  for (int mt = 0; mt < 2; mt++) {
    ahc[mt] = *(const half8*)(wA0h + Abase + tapLo * 8192 + mt * 512);
    alc[mt] = *(const half8*)(wA0l + Abase + tapLo * 8192 + mt * 512);
  }

  for (int tap = tapLo; tap < tapEnd; tap++) {
    half8 ahn[2], aln[2];
    {
      int tn = (tap + 1 < tapEnd) ? tap + 1 : tap;
#pragma unroll
      for (int mt = 0; mt < 2; mt++) {
        ahn[mt] = *(const half8*)(wA0h + Abase + tn * 8192 + mt * 512);
        aln[mt] = *(const half8*)(wA0l + Abase + tn * 8192 + mt * 512);
      }
    }
    int ky = tap / 5, kx = tap - ky * 5;
    int ix = l16 + kx - 2;
    bool oob = ((unsigned)ix > 15u);
#pragma unroll
    for (int nt = 0; nt < 4; nt++) {
      int pos = (nt + ky) * 16 + ix;     // slab row nt+ky in 0..7 (y-halo staged)
      if (oob) pos = 128;                // zero row (broadcast read)
      const _Float16* bp = sm + pos * 72 + bofs;
      half8 bh = *(const half8*)bp;
      half8 bl = *(const half8*)(bp + 9288);
#pragma unroll
      for (int mt = 0; mt < 2; mt++) {
        acch[nt][mt] = MFMA_F16(ahc[mt], bh, acch[nt][mt]);
        accl[nt][mt] = MFMA_F16(alc[mt], bh, accl[nt][mt]);
        accl[nt][mt] = MFMA_F16(ahc[mt], bl, accl[nt][mt]);
      }
    }
#pragma unroll
    for (int mt = 0; mt < 2; mt++) { ahc[mt] = ahn[mt]; alc[mt] = aln[mt]; }
  }

  // combine: slice s = cgl*2+tg (4 x [32][67]); kc1 waves write, kc0 waves +=
  __syncthreads();
  float* C = (float*)sm;
  if (kc == 1) {
    float* Cw = C + (cgl * 2 + tg) * 2144;
#pragma unroll
    for (int nt = 0; nt < 4; nt++) {
      int pos = nt * 16 + l16;
#pragma unroll
      for (int mt = 0; mt < 2; mt++)
#pragma unroll
        for (int r = 0; r < 4; r++)
          Cw[(mt * 16 + quad * 4 + r) * 67 + pos] = acch[nt][mt][r] + LO_SCALE * accl[nt][mt][r];
    }
  }
  __syncthreads();
  if (kc == 0) {
    float* Cw = C + (cgl * 2 + tg) * 2144;
#pragma unroll
    for (int nt = 0; nt < 4; nt++) {
      int pos = nt * 16 + l16;
#pragma unroll
      for (int mt = 0; mt < 2; mt++)
#pragma unroll
        for (int r = 0; r < 4; r++) {
          int a = (mt * 16 + quad * 4 + r) * 67 + pos;
          Cw[a] += acch[nt][mt][r] + LO_SCALE * accl[nt][mt][r];
        }
    }
  }
  __syncthreads();

  // epilogue: 2 windows/thread, co-INNER lanes (2 cgl x 32 co x 16 win; rows yq*2, yq*2+1)
  float pacc[10];
#pragma unroll
  for (int k = 0; k < 10; k++) pacc[k] = 0.f;

#pragma unroll
  for (int it2 = 0; it2 < 2; it2++) {
    int idx = it2 * 512 + tid;           // 1024 = cgl2 x win16 x co32 (co inner)
    int co = idx & 31, win = (idx >> 5) & 15, cgl2 = idx >> 9;
    int phl = win >> 3, pw = win & 7;
    int p0 = phl * 32 + pw * 2;
    int cbase = cgl2 * 4288;             // cgl2*2 slices of 2144
    int co_g = cgp * 64 + cgl2 * 32 + co;
    float bv = b0[co_g];
    float v[4];
#pragma unroll
    for (int q = 0; q < 4; q++) {
      int ci = co * 67 + p0 + (q >> 1) * 16 + (q & 1);
      float s = C[cbase + ci] + C[cbase + 2144 + ci];   // sum tg=0,1
      v[q] = s + bv;
    }
    float m0 = v[0]; int id = 0;
    if (v[1] > m0) { m0 = v[1]; id = 1; }
    if (v[2] > m0) { m0 = v[2]; id = 2; }
    if (v[3] > m0) { m0 = v[3]; id = 3; }
    int ph = yq * 2 + phl;
    int jj = ((cgp * 4 + yq) << 10) + idx;   // permuted internal s1/fcwp index
    int j = co_g * 64 + ph * 8 + pw;         // canonical (s1out, u)
    float sv = s1old[b * 8192 + jj];
    const float4* fp = (const float4*)(fcwp + jj * 12);
    float4 f0 = fp[0], f1 = fp[1], f2 = fp[2];
    float wv[10] = {f0.x, f0.y, f0.z, f0.w, f1.x, f1.y, f1.z, f1.w, f2.x, f2.y};
    float a = m0;
#pragma unroll
    for (int k = 0; k < 10; k++) {
      a += s0l[k] * wv[k];
      pacc[k] += sv * wv[k];      // s0 FC partial (reuses the fcwp load)
    }
    float r1 = rho_(a);
    s1new[b * 8192 + jj] = r1;
    if (s1out) s1out[b * 8192 + j] = r1;   // t=6/9: canonical s1 snapshot/final
    _Float16 hh, hl; split2(sv, hh, hl);
    half2v hv; hv[0] = hh; hv[1] = hl;
    unsigned pk = __builtin_bit_cast(unsigned, hv);
    int bu = (b * 256 + ph * 32 + pw * 2) * 128 + co_g;   // u32 units: [b][pos 256][cp 128]
    u[bu]        = (id == 0) ? pk : 0u;
    u[bu + 128]  = (id == 1) ? pk : 0u;
    u[bu + 2048] = (id == 2) ? pk : 0u;
    u[bu + 2176] = (id == 3) ? pk : 0u;
  }

  // s0 partial: wave butterfly -> LDS -> 10 plain stores per block (no atomics)
#pragma unroll
  for (int k = 0; k < 10; k++) {
    float vv = pacc[k];
#pragma unroll
    for (int off = 32; off > 0; off >>= 1) vv += __shfl_xor(vv, off);
    if (lane == 0) s0red[w][k] = vv;
  }
  __syncthreads();
  if (tid < 10) {
    float s = s0red[0][tid] + s0red[1][tid] + s0red[2][tid] + s0red[3][tid]
            + s0red[4][tid] + s0red[5][tid] + s0red[6][tid] + s0red[7][tid];
    s0curPart[((cgp * 4 + yq) * 64 + b) * 10 + tid] = s;
  }
}

// ---------------- K3: FUSED convT: full-K GEMM + rho(p2t+.)+split2 -> s2pk ----------------
// wave = kc(2 cp-half) x tg(4 tap-group {7,6,6,6}); nt=4 rows (whole y-quarter).
// Per iter (tap,cs): 4 A-loads (dbuf both planes) -> 24 MFMAs. 12-14 iters.
// grid (64 b, 2 oh, 4 yq) = 512 blocks. Stage: uint4 (4 cp) + half4 writes, 8 iters;
// x-zero-row at pos 128. LDS 70176 B. Tree-combine [4][32][67]; epilogue lane-major
// over o. s2out non-null (t=6/9): canonical s2 dual-store. s0fin non-null (t=9):
// designated blocks (oh==0,yq==0) write s0_10 from s0partCur (earlier conv0F dispatch).
__global__ __launch_bounds__(512, 4) void k_convTF(
    const unsigned* __restrict__ u,
    const _Float16* __restrict__ wA1h, const _Float16* __restrict__ wA1l,
    const float* __restrict__ p2t, unsigned* __restrict__ s2pk,
    float* __restrict__ s2out,
    const float* __restrict__ s0partCur, const float* __restrict__ fcb,
    float* __restrict__ s0fin) {
  __shared__ __align__(16) _Float16 sm[35088];   // 2 planes x [pos 129][136] = 70176 B
  int b = blockIdx.x, oh = blockIdx.y, yq = blockIdx.z, tid = threadIdx.x;

  if (s0fin && oh == 0 && yq == 0 && tid < 10) {   // t=9: s0_10 final
    float s = 0.f;
#pragma unroll
    for (int sl = 0; sl < 8; sl++) s += s0partCur[(sl * 64 + b) * 10 + tid];
    s0fin[b * 10 + tid] = rho_(s + fcb[tid]);
  }

  // stage: 4096 uint4-tasks (128 pl x 32 cp4), 8 iters; contiguous half4 LDS writes
#pragma unroll
  for (int it = 0; it < 8; it++) {
    int idx = it * 512 + tid;
    int cp4 = (idx & 31) * 4;
    int pl = idx >> 5;                 // 0..127
    int gy = yq * 4 - 2 + (pl >> 4);
    int lx = pl & 15;
    uint4 pk = {0u, 0u, 0u, 0u};
    if ((unsigned)gy < 16u) pk = *(const uint4*)&u[b * 32768 + (gy * 16 + lx) * 128 + cp4];
    half2v h0 = __builtin_bit_cast(half2v, pk.x);
    half2v h1 = __builtin_bit_cast(half2v, pk.y);
    half2v h2 = __builtin_bit_cast(half2v, pk.z);
    half2v h3 = __builtin_bit_cast(half2v, pk.w);
    half4 hi, lo;
    hi[0] = h0[0]; hi[1] = h1[0]; hi[2] = h2[0]; hi[3] = h3[0];
    lo[0] = h0[1]; lo[1] = h1[1]; lo[2] = h2[1]; lo[3] = h3[1];
    *(half4*)(sm + pl * 136 + cp4) = hi;
    *(half4*)(sm + 17544 + pl * 136 + cp4) = lo;
  }
  // zero row (pos 128) both planes: 136 halfs = 68 u32 each
  if (tid < 68) {
    ((unsigned*)sm)[8704 + tid] = 0u;            // 128*136/2
    ((unsigned*)sm)[8772 + 8704 + tid] = 0u;     // + plane offset 17544/2
  }
  __syncthreads();

  int lane = tid & 63, w = tid >> 6;
  int kc = w & 1, tg = w >> 1;
  int l16 = lane & 15, quad = lane >> 4;

  f32x4 acch[4][2], accl[4][2];   // [nt: 4 rows][mt]
#pragma unroll
  for (int nt = 0; nt < 4; nt++)
#pragma unroll
    for (int mt = 0; mt < 2; mt++) {
      f32x4 z; z[0] = 0.f; z[1] = 0.f; z[2] = 0.f; z[3] = 0.f;
      acch[nt][mt] = z; accl[nt][mt] = z;
    }

  const int Aoff = (oh * 32 + l16) * 32 + quad * 8;
  const int bofs = kc * 64 + quad * 8;
  const int tapLo = (tg == 0) ? 0 : 1 + 6 * tg;       // {0,7,13,19}
  const int itBeg = tapLo * 2;
  const int itEnd = (tapLo + ((tg == 0) ? 7 : 6)) * 2;

  half8 ahc[2], alc[2];
  {
    int Ab = (tapLo * 4 + kc * 2) * 2048;
#pragma unroll
    for (int mt = 0; mt < 2; mt++) {
      ahc[mt] = *(const half8*)(wA1h + Ab + Aoff + mt * 512);
      alc[mt] = *(const half8*)(wA1l + Ab + Aoff + mt * 512);
    }
  }

  for (int it = itBeg; it < itEnd; it++) {
    half8 ahn[2], aln[2];
    {
      int itn = (it + 1 < itEnd) ? it + 1 : it;
      int Abn = ((itn >> 1) * 4 + kc * 2 + (itn & 1)) * 2048;
#pragma unroll
      for (int mt = 0; mt < 2; mt++) {
        ahn[mt] = *(const half8*)(wA1h + Abn + Aoff + mt * 512);
        aln[mt] = *(const half8*)(wA1l + Abn + Aoff + mt * 512);
      }
    }
    int tap = it >> 1, cs = it & 1;
    int ky = tap / 5, kx = tap - ky * 5;
    int ix = l16 + 2 - kx;
    bool oob = ((unsigned)ix > 15u);
#pragma unroll
    for (int nt = 0; nt < 4; nt++) {
      int pos = (nt + 4 - ky) * 16 + ix;   // slab row in 0..7 (y-halo staged, never oob)
      if (oob) pos = 128;                  // zero row (broadcast read)
      const _Float16* bp = sm + pos * 136 + bofs + cs * 32;
      half8 bh = *(const half8*)bp;
      half8 bl = *(const half8*)(bp + 17544);
#pragma unroll
      for (int mt = 0; mt < 2; mt++) {
        acch[nt][mt] = MFMA_F16(ahc[mt], bh, acch[nt][mt]);
        accl[nt][mt] = MFMA_F16(alc[mt], bh, accl[nt][mt]);
        accl[nt][mt] = MFMA_F16(ahc[mt], bl, accl[nt][mt]);
      }
    }
#pragma unroll
    for (int mt = 0; mt < 2; mt++) { ahc[mt] = ahn[mt]; alc[mt] = aln[mt]; }
  }

  // tree-combine: waves 4-7 write slices [4][32][67]; waves 0-3 += into slice w
  __syncthreads();
  float* C = (float*)sm;
  if (w >= 4) {
    float* Cw = C + (w - 4) * 2144;
#pragma unroll
    for (int nt = 0; nt < 4; nt++) {
      int pos = nt * 16 + l16;
#pragma unroll
      for (int mt = 0; mt < 2; mt++)
#pragma unroll
        for (int r = 0; r < 4; r++)
          Cw[(mt * 16 + quad * 4 + r) * 67 + pos] = acch[nt][mt][r] + LO_SCALE * accl[nt][mt][r];
    }
  }
  __syncthreads();
  if (w < 4) {
    float* Cw = C + w * 2144;
#pragma unroll
    for (int nt = 0; nt < 4; nt++) {
      int pos = nt * 16 + l16;
#pragma unroll
      for (int mt = 0; mt < 2; mt++)
#pragma unroll
        for (int r = 0; r < 4; r++) {
          int a = (mt * 16 + quad * 4 + r) * 67 + pos;
          Cw[a] += acch[nt][mt][r] + LO_SCALE * accl[nt][mt][r];
        }
    }
  }
  __syncthreads();

  // epilogue: s2 = rho(p2t + sum4), split2, pack -> s2pk [b][pos][ch]; canonical dual-store
  int gbase = b * 16384 + yq * 4096 + oh * 32;
#pragma unroll
  for (int it = 0; it < 4; it++) {
    int m = it * 512 + tid;              // 2048 = 64 posl x 32 o
    int o = m & 31, posl = m >> 5;
    int ci = o * 67 + posl;
    float s = C[ci] + C[ci + 2144] + C[ci + 4288] + C[ci + 6432];
    int gi = gbase + posl * 64 + o;
    float v = rho_(p2t[gi] + s);
    _Float16 h, l; split2(v, h, l);
    half2v hv; hv[0] = h; hv[1] = l;
    s2pk[gi] = __builtin_bit_cast(unsigned, hv);
    if (s2out) s2out[b * 16384 + (oh * 32 + o) * 256 + yq * 64 + posl] = v;
  }
}

extern "C" void kernel_launch(void* const* d_in, const int* in_sizes, int n_in,
                              void* d_out, int out_size, void* d_ws, size_t ws_size,
                              hipStream_t stream) {
  const float* data   = (const float*)d_in[0];
  const float* s0init = (const float*)d_in[1];   // zeros
  const float* s1init = (const float*)d_in[2];   // zeros (permuted zeros == canonical zeros)
  const float* s2init = (const float*)d_in[3];   // zeros (t=0 conv0 input)
  const float* conv0w = (const float*)d_in[4];
  const float* conv0b = (const float*)d_in[5];
  const float* conv1w = (const float*)d_in[6];
  const float* conv1b = (const float*)d_in[7];
  const float* fcw    = (const float*)d_in[8];
  const float* fcb    = (const float*)d_in[9];
  (void)s0init; (void)s2init;

  // workspace (~23 MB of 256 MB)
  float* p = (float*)d_ws;
  float* s0part = p;                         p += 10240;     // 2 bufs x [slot 8][b 64][10]
  float* s1buf[2] = {p, p + 524288};         p += 1048576;   // permuted [b][jj 8192]
  float* p2t = p;                            p += 1048576;   // [b][pos 256][co 64]
  float* fcwp = p;                           p += 98304;     // [jj 8192][12]
  unsigned* u = (unsigned*)p;                p += 2097152;   // packed hi|lo [b][pos 256][cp 128]
  unsigned* s2pk = (unsigned*)p;             p += 1048576;   // packed split s2 [b][pos 256][ci 64]
  _Float16* hq = (_Float16*)p;
  _Float16* wA0h = hq;                       hq += 204800;
  _Float16* wA0l = hq;                       hq += 204800;
  _Float16* wA1h = hq;                       hq += 204800;
  _Float16* wA1l = hq;                       hq += 204800;

  k_prep<<<1056, 256, 0, stream>>>(conv0w, fcb, fcw, data, conv1w, conv1b,
                                   wA0h, wA0l, wA1h, wA1l, fcwp, s0part, p2t, s2pk);

  const float* s1o = s1init;
  float* outp = (float*)d_out;

  for (int t = 0; t < 10; t++) {
    int nb = t & 1;
    float* s1w = s1buf[nb];
    float* s1out = (t == 6) ? (outp + 1574144) : ((t == 9) ? (outp + 640) : nullptr);
    float* s0snap = (t == 7) ? (outp + 1573504) : nullptr;

    // conv0(s2_t from packed s2pk) + pool/argmax; s1_new = rho(p1 + fc^T(s0_t));
    // u = split(unpool(s1_old, idx)); s0 FC partials -> s0part buf[(t+1)&1]
    k_conv0F<<<dim3(64, 2, 4), 512, 0, stream>>>(s2pk,
                                                 wA0h, wA0l, conv0b,
                                                 s1o,
                                                 s0part + (t & 1) * 5120,
                                                 s0part + ((t + 1) & 1) * 5120,
                                                 fcb, fcwp, s1w, s1out, s0snap, u);
    // fused convT: full-K sum + rho(p2t+.)+split2 -> s2pk (+ canonical s2/s0 at t=6/9)
    float* s2out = (t == 6) ? (outp + 2098432) : ((t == 9) ? (outp + 524928) : nullptr);
    float* s0fin = (t == 9) ? outp : nullptr;
    k_convTF<<<dim3(64, 2, 4), 512, 0, stream>>>(u, wA1h, wA1l, p2t, s2pk,
                                                 s2out,
                                                 s0part + ((t + 1) & 1) * 5120, fcb,
                                                 s0fin);

    s1o = s1w;
  }
}

// Round 18
// 515.133 us; speedup vs baseline: 1.0383x; 1.0383x over previous
//
#include <hip/hip_runtime.h>

// convEP: 10-step EP relaxation, MFMA fp16 2-way-split convs (fp32-equivalent).
//   s0' = rho(fc(s1));  s1' = rho(pool(conv0(s2)) + fc^T(s0));  s2' = rho(p2 + convT(unpool(s1, idx1)))
// fp32 x = xh + 2^-12*xl' (fp16 planes, lo pre-scaled 2^12 to stay fp16-normal).
// MFMA 16x16x32_f16: A[m=l16][k=quad*8+j], B[k=quad*8+j][n=l16], C/D: col=l16, row=quad*4+reg.
// R31 (FINAL): revert to R28 exactly -- best measured (526.2us). R30's cTcomb-deletion/
// prep-merge was net-neutral-to-negative (+9us, within noise); R29 coop launch failed;
// R26 async staging regressed. Session 915 -> 526us (1.74x).
// Structure: R25 cg-pair conv0F + R20 tap-split convTF + R22/R23 tree-combine +
// R24 global relayout (conflict-free staging) + R28 co-inner epilogue/fcwp/permuted-s1.

typedef _Float16 half8 __attribute__((ext_vector_type(8)));
typedef _Float16 half4 __attribute__((ext_vector_type(4)));
typedef _Float16 half2v __attribute__((ext_vector_type(2)));
typedef float f32x4 __attribute__((ext_vector_type(4)));
#define MFMA_F16(A, B, C) __builtin_amdgcn_mfma_f32_16x16x32_f16((A), (B), (C), 0, 0, 0)
#define LO_SCALE 2.44140625e-4f   // 2^-12

static __device__ __forceinline__ float rho_(float x) {
  return fminf(fmaxf(x, 0.0f), 1.0f);
}
static __device__ __forceinline__ void split2(float v, _Float16& h, _Float16& l) {
  if (fabsf(v) < 6.1035156e-5f) {
    h = (_Float16)0.f;
    l = (_Float16)(v * 4096.f);
  } else {
    h = (_Float16)v;
    l = (_Float16)((v - (float)h) * 4096.f);
  }
}

// ---------------- K0: one-time weight split+transpose + fcwp + s0part init ----------------
// wA0[((tap*2+kc)*128 + co)*32 + cik] = conv0w[co][kc*32+cik][tap]
// wA1[((tap*4+c )*64  + o )*32 + cpk] = conv0w[(c*32+cpk)][o][tap]
// fcwp[jj*12 + k] = fcw[k*8192 + j(jj)] (k<10; pad 0) -- jj = conv0F epilogue thread order.
// s0part: 2 bufs x [slot 8][b 64][10]; buf0 slot0 = -fcb (so rho(sum+fcb)=0 at t=0), rest 0.
__global__ __launch_bounds__(256) void k_wprep(
    const float* __restrict__ w0, const float* __restrict__ fcb,
    const float* __restrict__ fcw,
    _Float16* __restrict__ wA0h, _Float16* __restrict__ wA0l,
    _Float16* __restrict__ wA1h, _Float16* __restrict__ wA1l,
    float* __restrict__ fcwp, float* __restrict__ s0part) {
  int i = blockIdx.x * 256 + threadIdx.x;
  if (i >= 204800) return;
  if (i < 10240) {
    int k = i - (i / 10) * 10;
    s0part[i] = (i < 640) ? -fcb[k] : 0.f;
  }
  if (i < 98304) {   // fcwp: 8192 jj x 12
    int jj = i / 12, k = i - jj * 12;
    int cgpyq = jj >> 10, idx = jj & 1023;
    int cgp = cgpyq >> 2, yq = cgpyq & 3;
    int co = idx & 31, win = (idx >> 5) & 15, cgl2 = idx >> 9;
    int co_g = cgp * 64 + cgl2 * 32 + co;
    int phl = win >> 3, pw = win & 7;
    int ph = yq * 2 + phl;
    int j = co_g * 64 + ph * 8 + pw;
    fcwp[i] = (k < 10) ? fcw[k * 8192 + j] : 0.f;
  }
  {
    int cik = i & 31, t1 = i >> 5;
    int co = t1 & 127, t2 = t1 >> 7;
    int ck = t2 & 1, tap = t2 >> 1;
    float v = w0[(co * 64 + ck * 32 + cik) * 25 + tap];
    _Float16 h, l; split2(v, h, l);
    wA0h[i] = h; wA0l[i] = l;
  }
  {
    int cpk = i & 31, t1 = i >> 5;
    int o = t1 & 63, t2 = t1 >> 6;
    int c = t2 & 3, tap = t2 >> 2;
    float v = w0[((c * 32 + cpk) * 64 + o) * 25 + tap];
    _Float16 h, l; split2(v, h, l);
    wA1h[i] = h; wA1l[i] = l;
  }
}

// ---------------- K1: p2t = transpose(maxpool2x2(conv2d(data, conv1_w) + conv1_b)) ----------------
// p2t layout: [b][pos 256][co 64] (pos = ph*16+pw) -- matches convTF epilogue lanes.
__global__ __launch_bounds__(256) void k_p2(
    const float* __restrict__ data, const float* __restrict__ w,
    const float* __restrict__ bias, float* __restrict__ p2t) {
  __shared__ float ld[3][36][36];
  __shared__ float lw[16][80];
  __shared__ float lb[16];
  int b = blockIdx.x, cg = blockIdx.y, tid = threadIdx.x;
  for (int i = tid; i < 3 * 36 * 36; i += 256) {
    int ci = i / 1296, rem = i % 1296, y = rem / 36, x = rem % 36;
    int gy = y - 2, gx = x - 2;
    float v = 0.f;
    if (gy >= 0 && gy < 32 && gx >= 0 && gx < 32)
      v = data[(b * 3 + ci) * 1024 + gy * 32 + gx];
    ld[ci][y][x] = v;
  }
  for (int i = tid; i < 16 * 75; i += 256) {
    int co = i / 75, k = i % 75;
    lw[co][k] = w[(cg * 16 + co) * 75 + k];
  }
  if (tid < 16) lb[tid] = bias[cg * 16 + tid];
  __syncthreads();
  int ph = tid >> 4, pw = tid & 15;
  int ry = 2 * ph, rx = 2 * pw;
  for (int co = 0; co < 16; co++) {
    float bv = lb[co];
    float a00 = bv, a01 = bv, a10 = bv, a11 = bv;
    for (int ci = 0; ci < 3; ci++) {
#pragma unroll
      for (int ky = 0; ky < 5; ky++) {
#pragma unroll
        for (int kx = 0; kx < 5; kx++) {
          float wv = lw[co][(ci * 5 + ky) * 5 + kx];
          a00 += wv * ld[ci][ry + ky][rx + kx];
          a01 += wv * ld[ci][ry + ky][rx + kx + 1];
          a10 += wv * ld[ci][ry + ky + 1][rx + kx];
          a11 += wv * ld[ci][ry + ky + 1][rx + kx + 1];
        }
      }
    }
    float m = fmaxf(fmaxf(a00, a01), fmaxf(a10, a11));
    p2t[b * 16384 + tid * 64 + cg * 16 + co] = m;
  }
}

// ---------------- K2: conv0 (cg-pair x y-quarter) + pool/argmax + s1 + u + s0 FC partial ----------------
// grid (64 b, 2 cgp, 4 yq) = 512 blocks, 512 thr = 8 waves = kc(2) x cgl(2) x tg(2 taps {13,12}).
// Staging: s2pk [b][pos][ci 64]: uint4 + half4 LDS writes, 4 iters; x-zero-row pos 128.
// Combine: 4 slices [cgl][tg][32][67]; kc1 write, kc0 +=. Epilogue co-inner lanes:
// C stride-67 reads, fcwp 3xfloat4, s1p [b][jj] coalesced both sides, u 128B segments.
// s1out non-null (t=6/9): canonical dual-store. launch_bounds(512,4).
__global__ __launch_bounds__(512, 4) void k_conv0F(
    const unsigned* __restrict__ s2pk,
    const _Float16* __restrict__ wA0h, const _Float16* __restrict__ wA0l,
    const float* __restrict__ b0,
    const float* __restrict__ s1old,
    const float* __restrict__ s0prevPart, float* __restrict__ s0curPart,
    const float* __restrict__ fcb,
    const float* __restrict__ fcwp, float* __restrict__ s1new,
    float* __restrict__ s1out,
    unsigned* __restrict__ u) {
  __shared__ __align__(16) _Float16 sm[18576];   // stage 37152 B; combine 4x[32][67] f32 34304 B
  __shared__ float s0l[10];
  __shared__ float s0red[8][10];
  int b = blockIdx.x, cgp = blockIdx.y, yq = blockIdx.z, tid = threadIdx.x;

  if (tid < 10) {   // s0_t = rho(sum of prev step's 8 slot partials + fcb); used in epilogue
    float s = 0.f;
#pragma unroll
    for (int sl = 0; sl < 8; sl++) s += s0prevPart[(sl * 64 + b) * 10 + tid];
    s0l[tid] = rho_(s + fcb[tid]);
  }

  // stage 8-row slab: s2pk[b][pos_g][ci]; 2048 uint4-tasks (128 pos x 16 ci4), 4 iters.
#pragma unroll
  for (int it = 0; it < 4; it++) {
    int idx = it * 512 + tid;
    int ci4 = (idx & 15) * 4;
    int pos = idx >> 4;                // 0..127 (ly*16+lx)
    int gy = yq * 4 - 2 + (pos >> 4);
    int lx = pos & 15;
    uint4 pk = {0u, 0u, 0u, 0u};
    if ((unsigned)gy < 16u) pk = *(const uint4*)&s2pk[b * 16384 + (gy * 16 + lx) * 64 + ci4];
    half2v h0 = __builtin_bit_cast(half2v, pk.x);
    half2v h1 = __builtin_bit_cast(half2v, pk.y);
    half2v h2 = __builtin_bit_cast(half2v, pk.z);
    half2v h3 = __builtin_bit_cast(half2v, pk.w);
    half4 hi, lo;
    hi[0] = h0[0]; hi[1] = h1[0]; hi[2] = h2[0]; hi[3] = h3[0];
    lo[0] = h0[1]; lo[1] = h1[1]; lo[2] = h2[1]; lo[3] = h3[1];
    *(half4*)(sm + pos * 72 + ci4) = hi;
    *(half4*)(sm + 9288 + pos * 72 + ci4) = lo;
  }
  // zero row (pos 128) in both planes: oob B-reads land here
  if (tid < 72) {
    sm[9216 + tid] = (_Float16)0.f;          // hi plane, pos 128
    sm[9288 + 9216 + tid] = (_Float16)0.f;   // lo plane, pos 128
  }
  __syncthreads();

  int lane = tid & 63, w = tid >> 6;
  int kc = w & 1, cgl = (w >> 1) & 1, tg = w >> 2;
  int l16 = lane & 15, quad = lane >> 4;

  f32x4 acch[4][2], accl[4][2];   // [nt: 4 rows][mt]  (bias in epilogue)
#pragma unroll
  for (int nt = 0; nt < 4; nt++)
#pragma unroll
    for (int mt = 0; mt < 2; mt++) {
      f32x4 z; z[0] = 0.f; z[1] = 0.f; z[2] = 0.f; z[3] = 0.f;
      acch[nt][mt] = z; accl[nt][mt] = z;
    }

  const int bofs = kc * 32 + quad * 8;
  const int Abase = (kc * 128 + (cgp * 2 + cgl) * 32 + l16) * 32 + quad * 8;  // + tap*8192 + mt*512
  const int tapLo = tg ? 13 : 0;
  const int tapEnd = tg ? 25 : 13;

  half8 ahc[2], alc[2];
#pragma unroll
  for (int mt = 0; mt < 2; mt++) {
    ahc[mt] = *(const half8*)(wA0h + Abase + tapLo * 8192 + mt * 512);
    alc[mt] = *(const half8*)(wA0l + Abase + tapLo * 8192 + mt * 512);
  }

  for (int tap = tapLo; tap < tapEnd; tap++) {
    half8 ahn[2], aln[2];
    {
      int tn = (tap + 1 < tapEnd) ? tap + 1 : tap;
#pragma unroll
      for (int mt = 0; mt < 2; mt++) {
        ahn[mt] = *(const half8*)(wA0h + Abase + tn * 8192 + mt * 512);
        aln[mt] = *(const half8*)(wA0l + Abase + tn * 8192 + mt * 512);
      }
    }
    int ky = tap / 5, kx = tap - ky * 5;
    int ix = l16 + kx - 2;
    bool oob = ((unsigned)ix > 15u);
#pragma unroll
    for (int nt = 0; nt < 4; nt++) {
      int pos = (nt + ky) * 16 + ix;     // slab row nt+ky in 0..7 (y-halo staged)
      if (oob) pos = 128;                // zero row (broadcast read)
      const _Float16* bp = sm + pos * 72 + bofs;
      half8 bh = *(const half8*)bp;
      half8 bl = *(const half8*)(bp + 9288);
#pragma unroll
      for (int mt = 0; mt < 2; mt++) {
        acch[nt][mt] = MFMA_F16(ahc[mt], bh, acch[nt][mt]);
        accl[nt][mt] = MFMA_F16(alc[mt], bh, accl[nt][mt]);
        accl[nt][mt] = MFMA_F16(ahc[mt], bl, accl[nt][mt]);
      }
    }
#pragma unroll
    for (int mt = 0; mt < 2; mt++) { ahc[mt] = ahn[mt]; alc[mt] = aln[mt]; }
  }

  // combine: slice s = cgl*2+tg (4 x [32][67]); kc1 waves write, kc0 waves +=
  __syncthreads();
  float* C = (float*)sm;
  if (kc == 1) {
    float* Cw = C + (cgl * 2 + tg) * 2144;
#pragma unroll
    for (int nt = 0; nt < 4; nt++) {
      int pos = nt * 16 + l16;
#pragma unroll
      for (int mt = 0; mt < 2; mt++)
#pragma unroll
        for (int r = 0; r < 4; r++)
          Cw[(mt * 16 + quad * 4 + r) * 67 + pos] = acch[nt][mt][r] + LO_SCALE * accl[nt][mt][r];
    }
  }
  __syncthreads();
  if (kc == 0) {
    float* Cw = C + (cgl * 2 + tg) * 2144;
#pragma unroll
    for (int nt = 0; nt < 4; nt++) {
      int pos = nt * 16 + l16;
#pragma unroll
      for (int mt = 0; mt < 2; mt++)
#pragma unroll
        for (int r = 0; r < 4; r++) {
          int a = (mt * 16 + quad * 4 + r) * 67 + pos;
          Cw[a] += acch[nt][mt][r] + LO_SCALE * accl[nt][mt][r];
        }
    }
  }
  __syncthreads();

  // epilogue: 2 windows/thread, co-INNER lanes (2 cgl x 32 co x 16 win; rows yq*2, yq*2+1)
  float pacc[10];
#pragma unroll
  for (int k = 0; k < 10; k++) pacc[k] = 0.f;

#pragma unroll
  for (int it2 = 0; it2 < 2; it2++) {
    int idx = it2 * 512 + tid;           // 1024 = cgl2 x win16 x co32 (co inner)
    int co = idx & 31, win = (idx >> 5) & 15, cgl2 = idx >> 9;
    int phl = win >> 3, pw = win & 7;
    int p0 = phl * 32 + pw * 2;
    int cbase = cgl2 * 4288;             // cgl2*2 slices of 2144
    int co_g = cgp * 64 + cgl2 * 32 + co;
    float bv = b0[co_g];
    float v[4];
#pragma unroll
    for (int q = 0; q < 4; q++) {
      int ci = co * 67 + p0 + (q >> 1) * 16 + (q & 1);
      float s = C[cbase + ci] + C[cbase + 2144 + ci];   // sum tg=0,1
      v[q] = s + bv;
    }
    float m0 = v[0]; int id = 0;
    if (v[1] > m0) { m0 = v[1]; id = 1; }
    if (v[2] > m0) { m0 = v[2]; id = 2; }
    if (v[3] > m0) { m0 = v[3]; id = 3; }
    int ph = yq * 2 + phl;
    int jj = ((cgp * 4 + yq) << 10) + idx;   // permuted internal s1/fcwp index
    int j = co_g * 64 + ph * 8 + pw;         // canonical (s1out, u)
    float sv = s1old[b * 8192 + jj];
    const float4* fp = (const float4*)(fcwp + jj * 12);
    float4 f0 = fp[0], f1 = fp[1], f2 = fp[2];
    float wv[10] = {f0.x, f0.y, f0.z, f0.w, f1.x, f1.y, f1.z, f1.w, f2.x, f2.y};
    float a = m0;
#pragma unroll
    for (int k = 0; k < 10; k++) {
      a += s0l[k] * wv[k];
      pacc[k] += sv * wv[k];      // s0 FC partial (reuses the fcwp load)
    }
    float r1 = rho_(a);
    s1new[b * 8192 + jj] = r1;
    if (s1out) s1out[b * 8192 + j] = r1;   // t=6/9: canonical s1 snapshot/final
    _Float16 hh, hl; split2(sv, hh, hl);
    half2v hv; hv[0] = hh; hv[1] = hl;
    unsigned pk = __builtin_bit_cast(unsigned, hv);
    int bu = (b * 256 + ph * 32 + pw * 2) * 128 + co_g;   // u32 units: [b][pos 256][cp 128]
    u[bu]        = (id == 0) ? pk : 0u;
    u[bu + 128]  = (id == 1) ? pk : 0u;
    u[bu + 2048] = (id == 2) ? pk : 0u;
    u[bu + 2176] = (id == 3) ? pk : 0u;
  }

  // s0 partial: wave butterfly -> LDS -> 10 plain stores per block (no atomics)
#pragma unroll
  for (int k = 0; k < 10; k++) {
    float vv = pacc[k];
#pragma unroll
    for (int off = 32; off > 0; off >>= 1) vv += __shfl_xor(vv, off);
    if (lane == 0) s0red[w][k] = vv;
  }
  __syncthreads();
  if (tid < 10) {
    float s = s0red[0][tid] + s0red[1][tid] + s0red[2][tid] + s0red[3][tid]
            + s0red[4][tid] + s0red[5][tid] + s0red[6][tid] + s0red[7][tid];
    s0curPart[((cgp * 4 + yq) * 64 + b) * 10 + tid] = s;
  }
}

// ---------------- K3: FUSED convT: full-K GEMM + rho(p2t+.)+split2 -> s2pk ----------------
// wave = kc(2 cp-half) x tg(4 tap-group {7,6,6,6}); nt=4 rows (whole y-quarter).
// Per iter (tap,cs): 4 A-loads (dbuf both planes) -> 24 MFMAs. 12-14 iters.
// grid (64 b, 2 oh, 4 yq) = 512 blocks. Stage: uint4 (4 cp) + half4 writes, 8 iters;
// x-zero-row at pos 128. LDS 70176 B. Tree-combine [4][32][67] (34.3KB); epilogue
// lane-major over o: stride-67 C reads = 32 banks; p2t/s2pk [pos][ch] coalesced.
__global__ __launch_bounds__(512, 4) void k_convTF(
    const unsigned* __restrict__ u,
    const _Float16* __restrict__ wA1h, const _Float16* __restrict__ wA1l,
    const float* __restrict__ p2t, unsigned* __restrict__ s2pk) {
  __shared__ __align__(16) _Float16 sm[35088];   // 2 planes x [pos 129][136] = 70176 B
  int b = blockIdx.x, oh = blockIdx.y, yq = blockIdx.z, tid = threadIdx.x;

  // stage: 4096 uint4-tasks (128 pl x 32 cp4), 8 iters; contiguous half4 LDS writes
#pragma unroll
  for (int it = 0; it < 8; it++) {
    int idx = it * 512 + tid;
    int cp4 = (idx & 31) * 4;
    int pl = idx >> 5;                 // 0..127
    int gy = yq * 4 - 2 + (pl >> 4);
    int lx = pl & 15;
    uint4 pk = {0u, 0u, 0u, 0u};
    if ((unsigned)gy < 16u) pk = *(const uint4*)&u[b * 32768 + (gy * 16 + lx) * 128 + cp4];
    half2v h0 = __builtin_bit_cast(half2v, pk.x);
    half2v h1 = __builtin_bit_cast(half2v, pk.y);
    half2v h2 = __builtin_bit_cast(half2v, pk.z);
    half2v h3 = __builtin_bit_cast(half2v, pk.w);
    half4 hi, lo;
    hi[0] = h0[0]; hi[1] = h1[0]; hi[2] = h2[0]; hi[3] = h3[0];
    lo[0] = h0[1]; lo[1] = h1[1]; lo[2] = h2[1]; lo[3] = h3[1];
    *(half4*)(sm + pl * 136 + cp4) = hi;
    *(half4*)(sm + 17544 + pl * 136 + cp4) = lo;
  }
  // zero row (pos 128) both planes: 136 halfs = 68 u32 each
  if (tid < 68) {
    ((unsigned*)sm)[8704 + tid] = 0u;            // 128*136/2
    ((unsigned*)sm)[8772 + 8704 + tid] = 0u;     // + plane offset 17544/2
  }
  __syncthreads();

  int lane = tid & 63, w = tid >> 6;
  int kc = w & 1, tg = w >> 1;
  int l16 = lane & 15, quad = lane >> 4;

  f32x4 acch[4][2], accl[4][2];   // [nt: 4 rows][mt]
#pragma unroll
  for (int nt = 0; nt < 4; nt++)
#pragma unroll
    for (int mt = 0; mt < 2; mt++) {
      f32x4 z; z[0] = 0.f; z[1] = 0.f; z[2] = 0.f; z[3] = 0.f;
      acch[nt][mt] = z; accl[nt][mt] = z;
    }

  const int Aoff = (oh * 32 + l16) * 32 + quad * 8;
  const int bofs = kc * 64 + quad * 8;
  const int tapLo = (tg == 0) ? 0 : 1 + 6 * tg;       // {0,7,13,19}
  const int itBeg = tapLo * 2;
  const int itEnd = (tapLo + ((tg == 0) ? 7 : 6)) * 2;

  half8 ahc[2], alc[2];
  {
    int Ab = (tapLo * 4 + kc * 2) * 2048;
#pragma unroll
    for (int mt = 0; mt < 2; mt++) {
      ahc[mt] = *(const half8*)(wA1h + Ab + Aoff + mt * 512);
      alc[mt] = *(const half8*)(wA1l + Ab + Aoff + mt * 512);
    }
  }

  for (int it = itBeg; it < itEnd; it++) {
    half8 ahn[2], aln[2];
    {
      int itn = (it + 1 < itEnd) ? it + 1 : it;
      int Abn = ((itn >> 1) * 4 + kc * 2 + (itn & 1)) * 2048;
#pragma unroll
      for (int mt = 0; mt < 2; mt++) {
        ahn[mt] = *(const half8*)(wA1h + Abn + Aoff + mt * 512);
        aln[mt] = *(const half8*)(wA1l + Abn + Aoff + mt * 512);
      }
    }
    int tap = it >> 1, cs = it & 1;
    int ky = tap / 5, kx = tap - ky * 5;
    int ix = l16 + 2 - kx;
    bool oob = ((unsigned)ix > 15u);
#pragma unroll
    for (int nt = 0; nt < 4; nt++) {
      int pos = (nt + 4 - ky) * 16 + ix;   // slab row in 0..7 (y-halo staged, never oob)
      if (oob) pos = 128;                  // zero row (broadcast read)
      const _Float16* bp = sm + pos * 136 + bofs + cs * 32;
      half8 bh = *(const half8*)bp;
      half8 bl = *(const half8*)(bp + 17544);
#pragma unroll
      for (int mt = 0; mt < 2; mt++) {
        acch[nt][mt] = MFMA_F16(ahc[mt], bh, acch[nt][mt]);
        accl[nt][mt] = MFMA_F16(alc[mt], bh, accl[nt][mt]);
        accl[nt][mt] = MFMA_F16(ahc[mt], bl, accl[nt][mt]);
      }
    }
#pragma unroll
    for (int mt = 0; mt < 2; mt++) { ahc[mt] = ahn[mt]; alc[mt] = aln[mt]; }
  }

  // tree-combine: waves 4-7 write slices [4][32][67]; waves 0-3 += into slice w
  __syncthreads();
  float* C = (float*)sm;
  if (w >= 4) {
    float* Cw = C + (w - 4) * 2144;
#pragma unroll
    for (int nt = 0; nt < 4; nt++) {
      int pos = nt * 16 + l16;
#pragma unroll
      for (int mt = 0; mt < 2; mt++)
#pragma unroll
        for (int r = 0; r < 4; r++)
          Cw[(mt * 16 + quad * 4 + r) * 67 + pos] = acch[nt][mt][r] + LO_SCALE * accl[nt][mt][r];
    }
  }
  __syncthreads();
  if (w < 4) {
    float* Cw = C + w * 2144;
#pragma unroll
    for (int nt = 0; nt < 4; nt++) {
      int pos = nt * 16 + l16;
#pragma unroll
      for (int mt = 0; mt < 2; mt++)
#pragma unroll
        for (int r = 0; r < 4; r++) {
          int a = (mt * 16 + quad * 4 + r) * 67 + pos;
          Cw[a] += acch[nt][mt][r] + LO_SCALE * accl[nt][mt][r];
        }
    }
  }
  __syncthreads();

  // epilogue: s2 = rho(p2t + sum4), split2, pack -> s2pk [b][pos][ch] (lane-major over o)
  int gbase = b * 16384 + yq * 4096 + oh * 32;
#pragma unroll
  for (int it = 0; it < 4; it++) {
    int m = it * 512 + tid;              // 2048 = 64 posl x 32 o
    int o = m & 31, posl = m >> 5;
    int ci = o * 67 + posl;
    float s = C[ci] + C[ci + 2144] + C[ci + 4288] + C[ci + 6432];
    int gi = gbase + posl * 64 + o;
    float v = rho_(p2t[gi] + s);
    _Float16 h, l; split2(v, h, l);
    half2v hv; hv[0] = h; hv[1] = l;
    s2pk[gi] = __builtin_bit_cast(unsigned, hv);
  }
}

// ---------------- K3b: s2 unpack(+transpose) + s0 finalize (t=6, t=9) ----------------
// blocks 0..255: s2 out = transpose-unpack(s2pk[b][pos][ci]) via 64x65 LDS tile;
// blocks 256..258: s0 = rho(sum 8 partials + fcb). (s1 copy fused into conv0F epilogue.)
__global__ __launch_bounds__(256) void k_cTcomb(
    const unsigned* __restrict__ s2pk, float* __restrict__ out_s2,
    const float* __restrict__ s0part, const float* __restrict__ fcb,
    float* __restrict__ out_s0) {
  int blk = blockIdx.x, tid = threadIdx.x;
  if (blk < 256) {
    __shared__ float tl[64 * 65];
    int b = blk >> 2, pt = blk & 3;      // pos tile pt*64..+63
    for (int it = 0; it < 16; it++) {
      int idx = it * 256 + tid;          // 4096 = 64 posl x 64 ci
      int ci = idx & 63, posl = idx >> 6;
      unsigned pk = s2pk[b * 16384 + (pt * 64 + posl) * 64 + ci];
      half2v hv = __builtin_bit_cast(half2v, pk);
      tl[posl * 65 + ci] = (float)hv[0] + LO_SCALE * (float)hv[1];
    }
    __syncthreads();
    for (int it = 0; it < 16; it++) {
      int idx = it * 256 + tid;
      int posl = idx & 63, ci = idx >> 6;
      out_s2[b * 16384 + ci * 256 + pt * 64 + posl] = tl[posl * 65 + ci];
    }
  } else {
    int i = (blk - 256) * 256 + tid;     // 640 s0 outputs
    if (i < 640) {
      int bb = i / 10, k = i - bb * 10;
      float s = 0.f;
#pragma unroll
      for (int sl = 0; sl < 8; sl++) s += s0part[(sl * 64 + bb) * 10 + k];
      out_s0[i] = rho_(s + fcb[k]);
    }
  }
}

extern "C" void kernel_launch(void* const* d_in, const int* in_sizes, int n_in,
                              void* d_out, int out_size, void* d_ws, size_t ws_size,
                              hipStream_t stream) {
  const float* data   = (const float*)d_in[0];
  const float* s0init = (const float*)d_in[1];   // zeros
  const float* s1init = (const float*)d_in[2];   // zeros (permuted zeros == canonical zeros)
  const float* s2init = (const float*)d_in[3];   // zeros (t=0 conv0 input)
  const float* conv0w = (const float*)d_in[4];
  const float* conv0b = (const float*)d_in[5];
  const float* conv1w = (const float*)d_in[6];
  const float* conv1b = (const float*)d_in[7];
  const float* fcw    = (const float*)d_in[8];
  const float* fcb    = (const float*)d_in[9];
  (void)s0init; (void)s2init;

  // workspace (~23 MB of 256 MB)
  float* p = (float*)d_ws;
  float* s0part = p;                         p += 10240;     // 2 bufs x [slot 8][b 64][10]
  float* s1buf[2] = {p, p + 524288};         p += 1048576;   // permuted [b][jj 8192]
  float* p2t = p;                            p += 1048576;   // [b][pos 256][co 64]
  float* fcwp = p;                           p += 98304;     // [jj 8192][12]
  unsigned* u = (unsigned*)p;                p += 2097152;   // packed hi|lo [b][pos 256][cp 128]
  unsigned* s2pk = (unsigned*)p;             p += 1048576;   // packed split s2 [b][pos 256][ci 64]
  _Float16* hq = (_Float16*)p;
  _Float16* wA0h = hq;                       hq += 204800;
  _Float16* wA0l = hq;                       hq += 204800;
  _Float16* wA1h = hq;                       hq += 204800;
  _Float16* wA1l = hq;                       hq += 204800;

  hipMemsetAsync(s2pk, 0, 1048576 * sizeof(unsigned), stream);   // t=0: s2 = 0 (packed split(0)=0)
  k_wprep<<<800, 256, 0, stream>>>(conv0w, fcb, fcw, wA0h, wA0l, wA1h, wA1l, fcwp, s0part);
  k_p2<<<dim3(64, 4), 256, 0, stream>>>(data, conv1w, conv1b, p2t);

  const float* s1o = s1init;
  float* outp = (float*)d_out;

  for (int t = 0; t < 10; t++) {
    int nb = t & 1;
    float* s1w = s1buf[nb];
    float* s1out = (t == 6) ? (outp + 1574144) : ((t == 9) ? (outp + 640) : nullptr);

    // conv0(s2_t from packed s2pk) + pool/argmax; s1_new = rho(p1 + fc^T(s0_t));
    // u = split(unpool(s1_old, idx)); s0 FC partials -> s0part buf[(t+1)&1]
    k_conv0F<<<dim3(64, 2, 4), 512, 0, stream>>>(s2pk,
                                                 wA0h, wA0l, conv0b,
                                                 s1o,
                                                 s0part + (t & 1) * 5120,
                                                 s0part + ((t + 1) & 1) * 5120,
                                                 fcb, fcwp, s1w, s1out, u);
    // fused convT (tap-split waves): full-K sum + rho(p2t+.)+split2 -> s2pk
    k_convTF<<<dim3(64, 2, 4), 512, 0, stream>>>(u, wA1h, wA1l, p2t, s2pk);

    s1o = s1w;

    if (t == 6) {   // PRED_T snapshot: s0_7, s2_7 -> d_out (s1_7 written by conv0F)
      k_cTcomb<<<259, 256, 0, stream>>>(s2pk, outp + 2098432,
                                        s0part + 5120, fcb, outp + 1573504);
    }
  }

  // final states: s0_10 (partials in buf[0]), s2_10 -> d_out (s1_10 written by conv0F)
  k_cTcomb<<<259, 256, 0, stream>>>(s2pk, outp + 524928,
                                    s0part, fcb, outp + 0);
}